// Round 9
// baseline (827.313 us; speedup 1.0000x reference)
//
#include <hip/hip_runtime.h>
#include <hip/hip_bf16.h>

// ---------- types / helpers ----------
typedef __attribute__((ext_vector_type(8))) short short8;   // 8 bf16 (4 VGPRs)
typedef __attribute__((ext_vector_type(4))) float f32x4;

__device__ __forceinline__ float bf2f(unsigned short u) {
    return __builtin_bit_cast(float, (unsigned int)u << 16);
}
__device__ __forceinline__ unsigned short f2bf(float f) {
    unsigned int i = __builtin_bit_cast(unsigned int, f);
    i += 0x7fffu + ((i >> 16) & 1u);          // RNE
    return (unsigned short)(i >> 16);
}
__device__ __forceinline__ void bfx2(unsigned int u, float& lo, float& hi) {
    lo = __builtin_bit_cast(float, u << 16);
    hi = __builtin_bit_cast(float, u & 0xffff0000u);
}

#define FIXP 8388608.0f   /* 2^23 fixed-point scale for degree accumulation */
#define BKT_SHIFT 7
#define BKT_W 128         /* cols per bucket */
#define GB 256            /* edge-chunk blocks for hist/scatter */
#define SCAN_BS 1024
#define SLICES 8          /* feature slices: 16 features = 3.2MB/slice, fits XCD L2 */
#define AGG_BLOCKS 2048   /* 8 blocks/CU; blockIdx&7 -> XCD (round-robin mapping) */

// ---------- dtype detector ----------
__global__ void detect_k(const unsigned int* xw, const unsigned int* ei, int* flags) {
    __shared__ int cnt14;
    __shared__ unsigned int orodd;
    if (threadIdx.x == 0) { cnt14 = 0; orodd = 0u; }
    __syncthreads();
    int c = 0; unsigned int o = 0u;
    for (int i = threadIdx.x; i < 4096; i += 256) {
        c += (int)((xw[i] >> 14) & 1u);
        o |= ei[2 * i + 1];
    }
    atomicAdd(&cnt14, c);
    atomicOr(&orodd, o);
    __syncthreads();
    if (threadIdx.x == 0) {
        flags[0] = (cnt14 > 1024) ? 1 : 0;
        flags[1] = (orodd == 0u) ? 1 : 0;
    }
}

__device__ __forceinline__ int load_row(const int* ei, int e, int i64f) {
    return i64f ? ei[2 * (size_t)e] : ei[e];
}
__device__ __forceinline__ int load_col(const int* ei, int e, int E, int i64f) {
    return i64f ? ei[2 * (size_t)E + 2 * (size_t)e] : ei[(size_t)E + e];
}
__device__ __forceinline__ float load_w(const void* w, int e, int f32f) {
    return f32f ? ((const float*)w)[e] : bf2f(((const unsigned short*)w)[e]);
}

// ---------- pass A: per-(block, bucket) histogram (LDS atomics only) ----------
__global__ __launch_bounds__(1024) void hist_k(const int* ei, unsigned int* gh,
                                               int E, int NB, int chunk,
                                               const int* flags) {
    __shared__ unsigned int lh[1024];
    for (int b = threadIdx.x; b < 1024; b += 1024) lh[b] = 0u;
    __syncthreads();
    int i64f = flags[1];
    int blk = blockIdx.x;
    int s = blk * chunk;
    int t = min(s + chunk, E);
    for (int i = s + threadIdx.x; i < t; i += 1024) {
        int c = load_col(ei, i, E, i64f);
        atomicAdd(&lh[c >> BKT_SHIFT], 1u);
    }
    __syncthreads();
    for (int b = threadIdx.x; b < NB; b += 1024)
        gh[(size_t)b * GB + blk] = lh[b];     // bucket-major, block-minor
}

// ---------- scans (for the gh table) ----------
__global__ void scan1_k(const int* counts, int* offsets, int* partials, int n) {
    __shared__ int buf[SCAN_BS];
    int t = threadIdx.x, g = blockIdx.x * SCAN_BS + t;
    int v = (g < n) ? counts[g] : 0;
    buf[t] = v; __syncthreads();
    for (int off = 1; off < SCAN_BS; off <<= 1) {
        int x = (t >= off) ? buf[t - off] : 0;
        __syncthreads();
        buf[t] += x;
        __syncthreads();
    }
    if (g < n) offsets[g] = buf[t] - v;                 // exclusive
    if (t == SCAN_BS - 1) partials[blockIdx.x] = buf[t];
}

__global__ void scan2_k(int* partials, int n) {         // n <= 1024
    __shared__ int buf[SCAN_BS];
    int t = threadIdx.x;
    int v = (t < n) ? partials[t] : 0;
    buf[t] = v; __syncthreads();
    for (int off = 1; off < SCAN_BS; off <<= 1) {
        int x = (t >= off) ? buf[t - off] : 0;
        __syncthreads();
        buf[t] += x;
        __syncthreads();
    }
    if (t < n) partials[t] = buf[t] - v;                // exclusive
}

__global__ void scan3_k(int* offsets, const int* partials, int n) {
    int g = blockIdx.x * SCAN_BS + threadIdx.x;
    if (g < n) offsets[g] += partials[blockIdx.x];
}

// ---------- pass B: scatter edges into bucket-grouped 8B packed records ----
// Record: u64 = w_bits<<32 | row<<7 | (col & 127).
__global__ __launch_bounds__(1024) void scatter_k(const int* ei, const void* w,
                                                  const unsigned int* gh,
                                                  unsigned long long* rc,
                                                  int E, int NB, int chunk,
                                                  const int* flags) {
    __shared__ unsigned int cur[1024];
    int blk = blockIdx.x;
    for (int b = threadIdx.x; b < NB; b += 1024)
        cur[b] = gh[(size_t)b * GB + blk];
    __syncthreads();
    int f32f = flags[0], i64f = flags[1];
    int s = blk * chunk, t = min(s + chunk, E);
    for (int i = s + threadIdx.x; i < t; i += 1024) {
        int c = load_col(ei, i, E, i64f);
        int r = load_row(ei, i, i64f);
        float wf = load_w(w, i, f32f);
        unsigned int pos = atomicAdd(&cur[c >> BKT_SHIFT], 1u);
        unsigned long long rec =
            ((unsigned long long)(unsigned int)__float_as_int(wf) << 32) |
            (unsigned int)((r << 7) | (c & (BKT_W - 1)));
        rc[pos] = rec;
    }
}

// ---------- merged per-bucket finalize: count + local scan + place ----------
__global__ __launch_bounds__(256) void bucket_fin_k(const unsigned long long* rc,
                                                    const unsigned int* gh,
                                                    float* dinv,
                                                    int* offsets, int2* edata,
                                                    int E, int N, int NB) {
    __shared__ unsigned long long pk[BKT_W];
    __shared__ unsigned int sc[BKT_W];
    __shared__ unsigned int cur[BKT_W];
    int b = blockIdx.x;
    for (int i = threadIdx.x; i < BKT_W; i += 256) pk[i] = 0ULL;
    __syncthreads();
    unsigned int s = gh[(size_t)b * GB];
    unsigned int t = (b + 1 < NB) ? gh[(size_t)(b + 1) * GB] : (unsigned int)E;
    for (unsigned int i = s + threadIdx.x; i < t; i += 256) {
        unsigned long long rec = rc[i];
        float wf = __int_as_float((int)(unsigned int)(rec >> 32));
        unsigned int wq = __float2uint_rn(wf * FIXP);
        atomicAdd(&pk[(unsigned int)rec & (BKT_W - 1)],
                  (1ULL << 32) | (unsigned long long)wq);
    }
    __syncthreads();
    unsigned int val = 0;
    if (threadIdx.x < BKT_W) {
        val = (unsigned int)(pk[threadIdx.x] >> 32);
        sc[threadIdx.x] = val;
    }
    __syncthreads();
    for (int off = 1; off < BKT_W; off <<= 1) {
        unsigned int x = (threadIdx.x < BKT_W && threadIdx.x >= (unsigned)off)
                             ? sc[threadIdx.x - off] : 0u;
        __syncthreads();
        if (threadIdx.x < BKT_W) sc[threadIdx.x] += x;
        __syncthreads();
    }
    if (threadIdx.x < BKT_W) {
        int lc = threadIdx.x;
        int v = (b << BKT_SHIFT) + lc;
        unsigned int off0 = s + sc[lc] - val;           // exclusive, bucket-based
        cur[lc] = off0;
        if (v < N) {
            unsigned long long p = pk[lc];
            float deg = 1.0f + (float)(unsigned int)(p & 0xffffffffULL) * (1.0f / FIXP);
            dinv[v] = rsqrtf(deg);                      // deg >= 1 (self loop)
            offsets[v] = (int)off0;
        }
    }
    if (b == NB - 1 && threadIdx.x == 0) offsets[N] = E;
    __syncthreads();
    for (unsigned int i = s + threadIdx.x; i < t; i += 256) {
        unsigned long long rec = rc[i];
        unsigned int lo = (unsigned int)rec;
        unsigned int pos = atomicAdd(&cur[lo & (BKT_W - 1)], 1u);
        int2 o; o.x = (int)(lo >> 7); o.y = (int)(unsigned int)(rec >> 32);
        edata[pos] = o;                                 // (row, w_bits)
    }
}

// ---------- both weight transposes in one launch ----------
__global__ void transpose2_k(const void* W1, const void* W2,
                             unsigned short* Wt1, unsigned short* Wt2,
                             const int* flags) {
    int i = blockIdx.x * 256 + threadIdx.x;             // 0..32767
    int which = i >> 14, j = i & 16383;
    const void* W = which ? W2 : W1;
    unsigned short* Wt = which ? Wt2 : Wt1;
    int k = j >> 7, n = j & 127;
    unsigned short v = flags[0] ? f2bf(((const float*)W)[j])
                                : ((const unsigned short*)W)[j];
    Wt[n * 128 + k] = v;
}

// ---------- GEMM: hs = dinv[r] * (X @ W), written in SLICED layout ----------
// Output slice s = features [s*16, s*16+16): u16 at  s*N*16 + r*16 + m.
// The ct-tile IS the slice (ct = 0..7 covers 16 cols each).
// xmode=1 input X is itself sliced (a1 from layer-1 agg).
__global__ __launch_bounds__(256) void gemm_k(const void* X,
                                              const unsigned short* Wt,
                                              const float* dinv,
                                              unsigned short* Y, int ntiles,
                                              const int* flags, int xmode, int N) {
    int wave = blockIdx.x * 4 + (threadIdx.x >> 6);
    if (wave >= ntiles) return;
    int lane = threadIdx.x & 63;
    int m = lane & 15, quad = lane >> 4;
    int rowbase = wave * 16;
    int x_f32 = (xmode == 0) ? flags[0] : 0;

    short8 a[4];
    if (x_f32) {
        const float* xf = (const float*)X;
#pragma unroll
        for (int ks = 0; ks < 4; ++ks) {
            const float* p = xf + (size_t)(rowbase + m) * 128 + ks * 32 + quad * 8;
            float4 u0 = *(const float4*)p;
            float4 u1 = *(const float4*)(p + 4);
            short8 t;
            t[0] = (short)f2bf(u0.x); t[1] = (short)f2bf(u0.y);
            t[2] = (short)f2bf(u0.z); t[3] = (short)f2bf(u0.w);
            t[4] = (short)f2bf(u1.x); t[5] = (short)f2bf(u1.y);
            t[6] = (short)f2bf(u1.z); t[7] = (short)f2bf(u1.w);
            a[ks] = t;
        }
    } else if (xmode == 0) {
        const unsigned short* xh = (const unsigned short*)X;
#pragma unroll
        for (int ks = 0; ks < 4; ++ks)
            a[ks] = *(const short8*)(xh + (size_t)(rowbase + m) * 128 + ks * 32 + quad * 8);
    } else {
        // sliced input: features k0 = ks*32+quad*8 live in slice k0>>4 at off k0&15
        const unsigned short* xh = (const unsigned short*)X;
#pragma unroll
        for (int ks = 0; ks < 4; ++ks) {
            int k0 = ks * 32 + quad * 8;
            a[ks] = *(const short8*)(xh + (size_t)(k0 >> 4) * N * 16 +
                                     (size_t)(rowbase + m) * 16 + (k0 & 15));
        }
    }

    float dvr[4];
#pragma unroll
    for (int i = 0; i < 4; ++i) dvr[i] = dinv[rowbase + quad * 4 + i];

#pragma unroll
    for (int ct = 0; ct < 8; ++ct) {
        f32x4 acc = {0.f, 0.f, 0.f, 0.f};
#pragma unroll
        for (int ks = 0; ks < 4; ++ks) {
            short8 b = *(const short8*)(Wt + (size_t)(ct * 16 + m) * 128 + ks * 32 + quad * 8);
            acc = __builtin_amdgcn_mfma_f32_16x16x32_bf16(a[ks], b, acc, 0, 0, 0);
        }
#pragma unroll
        for (int i = 0; i < 4; ++i) {
            size_t r = rowbase + quad * 4 + i;
            Y[(size_t)ct * N * 16 + r * 16 + m] = f2bf(acc[i] * dvr[i]);
        }
    }
}

// ---------- aggregation, XCD-feature-sliced ----------
// slice = blockIdx&7 -> pinned to one XCD (HW round-robin); that XCD gathers
// only from its 3.2MB h-slice => L2-resident. Lane = (edge group g=lane>>2,
// dword-pair dw2=lane&3): 16 edges per wave memory op; shfl_xor reduce.
__global__ __launch_bounds__(256) void agg_k(const uint2* hv,      // sliced h
                                             const int2* edata,
                                             const int* offsets,
                                             const float* dinv,
                                             const void* bias,
                                             void* out,
                                             int relu, int out_bf16,
                                             const int* flags, int N, int npw) {
    int slice = blockIdx.x & 7;
    int wave  = (blockIdx.x >> 3) * 4 + (threadIdx.x >> 6);
    int lane  = threadIdx.x & 63;
    int g   = lane >> 2;
    int dw2 = lane & 3;
    const uint2* hs = hv + (size_t)slice * N * 4;
    int f32f = flags[0];

    int v0 = wave * npw;
    int v1 = min(N, v0 + npw);
    for (int v = v0; v < v1; ++v) {
        int2 se = *(const int2*)(offsets + v);
        int start = se.x, end = se.y;
        float a0 = 0.f, a1 = 0.f, a2 = 0.f, a3 = 0.f;
        for (int e = start; e < end; e += 16) {
            int idx = e + g;
            bool valid = idx < end;
            int idxc = valid ? idx : end - 1;
            int2 d = edata[idxc];                        // (row, w_bits)
            float c = valid ? __int_as_float(d.y) : 0.f;
            uint2 u = hs[(size_t)d.x * 4 + dw2];
            float l0, h0, l1, h1;
            bfx2(u.x, l0, h0); bfx2(u.y, l1, h1);
            a0 = fmaf(c, l0, a0); a1 = fmaf(c, h0, a1);
            a2 = fmaf(c, l1, a2); a3 = fmaf(c, h1, a3);
        }
#pragma unroll
        for (int mk = 4; mk < 64; mk <<= 1) {
            a0 += __shfl_xor(a0, mk, 64);
            a1 += __shfl_xor(a1, mk, 64);
            a2 += __shfl_xor(a2, mk, 64);
            a3 += __shfl_xor(a3, mk, 64);
        }
        {   // self loop: hs[v], coefficient 1 (hs carries dinv[row])
            uint2 u = hs[(size_t)v * 4 + dw2];
            float l0, h0, l1, h1;
            bfx2(u.x, l0, h0); bfx2(u.y, l1, h1);
            a0 += l0; a1 += h0; a2 += l1; a3 += h1;
        }
        float dv = dinv[v];
        a0 *= dv; a1 *= dv; a2 *= dv; a3 *= dv;
        if (f32f) {
            float4 bq = ((const float4*)((const float*)bias + slice * 16))[dw2];
            a0 += bq.x; a1 += bq.y; a2 += bq.z; a3 += bq.w;
        } else {
            uint2 bu = ((const uint2*)bias)[slice * 4 + dw2];
            float l0, h0, l1, h1;
            bfx2(bu.x, l0, h0); bfx2(bu.y, l1, h1);
            a0 += l0; a1 += h0; a2 += l1; a3 += h1;
        }
        if (relu) {
            a0 = fmaxf(a0, 0.f); a1 = fmaxf(a1, 0.f);
            a2 = fmaxf(a2, 0.f); a3 = fmaxf(a3, 0.f);
        }
        if (lane < 4) {
            if (out_bf16) {
                uint2 o;
                o.x = (unsigned int)f2bf(a0) | ((unsigned int)f2bf(a1) << 16);
                o.y = (unsigned int)f2bf(a2) | ((unsigned int)f2bf(a3) << 16);
                ((uint2*)out)[(size_t)slice * N * 4 + (size_t)v * 4 + dw2] = o;
            } else {
                float4 o; o.x = a0; o.y = a1; o.z = a2; o.w = a3;
                ((float4*)((float*)out + (size_t)v * 128 + slice * 16))[dw2] = o;
            }
        }
    }
}

// ---------- launch ----------
extern "C" void kernel_launch(void* const* d_in, const int* in_sizes, int n_in,
                              void* d_out, int out_size, void* d_ws, size_t ws_size,
                              hipStream_t stream) {
    const void* x  = d_in[0];                 // fp32 (detected) [N,128]
    const int*  ei = (const int*)d_in[1];     // int64/int32 (detected) [2,E]
    const void* ew = d_in[2];                 // fp32 [E]
    const void* W1 = d_in[3];
    const void* b1 = d_in[4];
    const void* W2 = d_in[5];
    const void* b2 = d_in[6];

    const int N = in_sizes[0] / 128;     // 100000
    const int E = in_sizes[2];           // 3200000

    const int NB = (N + BKT_W - 1) >> BKT_SHIFT;   // 782 buckets
    if (NB > 1024) return;                         // design limit N <= 131072 (row fits 17 bits)
    const int M = NB * GB;                         // gh table entries (200192)
    const int chunk = (E + GB - 1) / GB;

    auto align = [](size_t v) { return (v + 255) & ~(size_t)255; };
    size_t rc_bytes = align((size_t)E * 8);
    size_t ha_bytes = 2 * align((size_t)N * 128 * 2);
    size_t regionX  = rc_bytes > ha_bytes ? rc_bytes : ha_bytes;
    size_t need = align((size_t)E * 8)            // edata
                + regionX                         // rc | h,a1
                + align((size_t)M * 4)            // gh
                + align((size_t)(N + 1) * 4)      // offsets (N+1)
                + align((size_t)N * 4)            // dinv
                + align(SCAN_BS * 4) + align(256) // partials, flags
                + align(128 * 128 * 2) * 2;       // Wt1, Wt2
    if (ws_size < need) return;  // diagnostic: zeros -> absmax 0.3613

    char* p = (char*)d_ws;
    int2*  edata = (int2*)p;                     p += align((size_t)E * 8);
    char*  rx = p;                               p += regionX;
    unsigned long long* rc = (unsigned long long*)rx;
    unsigned short* h  = (unsigned short*)rx;
    unsigned short* a1 = (unsigned short*)(rx + align((size_t)N * 128 * 2));
    unsigned int* gh = (unsigned int*)p;         p += align((size_t)M * 4);
    int*   offsets  = (int*)p;                   p += align((size_t)(N + 1) * 4);
    float* dinv     = (float*)p;                 p += align((size_t)N * 4);
    int*   partials = (int*)p;                   p += align(SCAN_BS * 4);
    int*   flags    = (int*)p;                   p += align(256);
    unsigned short* Wt1 = (unsigned short*)p;    p += align(128 * 128 * 2);
    unsigned short* Wt2 = (unsigned short*)p;    p += align(128 * 128 * 2);

    const int nsbM = (M + SCAN_BS - 1) / SCAN_BS;    // 196

    detect_k<<<1, 256, 0, stream>>>((const unsigned int*)x, (const unsigned int*)ei, flags);

    // ---- bucket sort (no global atomics anywhere) ----
    hist_k<<<GB, 1024, 0, stream>>>(ei, gh, E, NB, chunk, flags);
    scan1_k<<<nsbM, SCAN_BS, 0, stream>>>((const int*)gh, (int*)gh, partials, M);
    scan2_k<<<1, SCAN_BS, 0, stream>>>(partials, nsbM);
    scan3_k<<<nsbM, SCAN_BS, 0, stream>>>((int*)gh, partials, M);
    scatter_k<<<GB, 1024, 0, stream>>>(ei, ew, gh, rc, E, NB, chunk, flags);
    bucket_fin_k<<<NB, 256, 0, stream>>>(rc, gh, dinv, offsets, edata, E, N, NB);

    transpose2_k<<<128, 256, 0, stream>>>(W1, W2, Wt1, Wt2, flags);

    const int ntiles = N / 16;                       // 6250
    const int gGemm = (ntiles + 3) / 4;
    const int nwaves = (AGG_BLOCKS / 8) * 4;         // waves per slice (1024)
    const int npw = (N + nwaves - 1) / nwaves;       // nodes per wave

    // layer 1: hs = dinv*(x@W1) sliced ; a1 = relu(agg(hs) + b1) sliced
    gemm_k<<<gGemm, 256, 0, stream>>>(x, Wt1, dinv, h, ntiles, flags, /*xmode=*/0, N);
    agg_k<<<AGG_BLOCKS, 256, 0, stream>>>((const uint2*)h, edata, offsets, dinv,
                                          b1, a1, /*relu=*/1, /*out_bf16=*/1,
                                          flags, N, npw);

    // layer 2: hs = dinv*(a1@W2) sliced ; out = agg(hs) + b2  (fp32, row-major)
    gemm_k<<<gGemm, 256, 0, stream>>>(a1, Wt2, dinv, h, ntiles, flags, /*xmode=*/1, N);
    agg_k<<<AGG_BLOCKS, 256, 0, stream>>>((const uint2*)h, edata, offsets, dinv,
                                          b2, d_out, /*relu=*/0, /*out_bf16=*/0,
                                          flags, N, npw);
}

// Round 11
// 520.731 us; speedup vs baseline: 1.5888x; 1.5888x over previous
//
#include <hip/hip_runtime.h>
#include <hip/hip_bf16.h>

// ---------- types / helpers ----------
typedef __attribute__((ext_vector_type(8))) short short8;   // 8 bf16 (4 VGPRs)
typedef __attribute__((ext_vector_type(4))) float f32x4;

__device__ __forceinline__ float bf2f(unsigned short u) {
    return __builtin_bit_cast(float, (unsigned int)u << 16);
}
__device__ __forceinline__ unsigned short f2bf(float f) {
    unsigned int i = __builtin_bit_cast(unsigned int, f);
    i += 0x7fffu + ((i >> 16) & 1u);          // RNE
    return (unsigned short)(i >> 16);
}
__device__ __forceinline__ void bfx2(unsigned int u, float& lo, float& hi) {
    lo = __builtin_bit_cast(float, u << 16);
    hi = __builtin_bit_cast(float, u & 0xffff0000u);
}

#define FIXP 8388608.0f   /* 2^23 fixed-point scale for degree accumulation */
#define BKT_SHIFT 7
#define BKT_W 128         /* cols per bucket */
#define GB 256            /* edge-chunk blocks for hist/scatter */
#define SCAN_BS 1024

// ---------- dtype detector ----------
// flags[0] = 1 if float tensors are fp32 (else packed bf16)
// flags[1] = 1 if edge_index is int64 (else int32)
__global__ void detect_k(const unsigned int* xw, const unsigned int* ei, int* flags) {
    __shared__ int cnt14;
    __shared__ unsigned int orodd;
    if (threadIdx.x == 0) { cnt14 = 0; orodd = 0u; }
    __syncthreads();
    int c = 0; unsigned int o = 0u;
    for (int i = threadIdx.x; i < 4096; i += 256) {
        c += (int)((xw[i] >> 14) & 1u);
        o |= ei[2 * i + 1];
    }
    atomicAdd(&cnt14, c);
    atomicOr(&orodd, o);
    __syncthreads();
    if (threadIdx.x == 0) {
        flags[0] = (cnt14 > 1024) ? 1 : 0;
        flags[1] = (orodd == 0u) ? 1 : 0;
    }
}

__device__ __forceinline__ int load_row(const int* ei, int e, int i64f) {
    return i64f ? ei[2 * (size_t)e] : ei[e];
}
__device__ __forceinline__ int load_col(const int* ei, int e, int E, int i64f) {
    return i64f ? ei[2 * (size_t)E + 2 * (size_t)e] : ei[(size_t)E + e];
}
__device__ __forceinline__ float load_w(const void* w, int e, int f32f) {
    return f32f ? ((const float*)w)[e] : bf2f(((const unsigned short*)w)[e]);
}

// pair loads (chunk start is even, so e is even where used)
__device__ __forceinline__ void load_col2(const int* ei, int e, int E, int i64f,
                                          int& c0, int& c1) {
    if (i64f) { int4 q = *(const int4*)(ei + 2 * (size_t)E + 2 * (size_t)e); c0 = q.x; c1 = q.z; }
    else      { int2 q = *(const int2*)(ei + (size_t)E + e); c0 = q.x; c1 = q.y; }
}
__device__ __forceinline__ void load_row2(const int* ei, int e, int i64f,
                                          int& r0, int& r1) {
    if (i64f) { int4 q = *(const int4*)(ei + 2 * (size_t)e); r0 = q.x; r1 = q.z; }
    else      { int2 q = *(const int2*)(ei + e); r0 = q.x; r1 = q.y; }
}
__device__ __forceinline__ void load_w2(const void* w, int e, int f32f,
                                        float& w0, float& w1) {
    if (f32f) { float2 q = *(const float2*)((const float*)w + e); w0 = q.x; w1 = q.y; }
    else {
        unsigned int q = *(const unsigned int*)((const unsigned short*)w + e);
        w0 = bf2f((unsigned short)q); w1 = bf2f((unsigned short)(q >> 16));
    }
}

// ---------- pass A: per-(block, bucket) histogram (LDS atomics only) ----------
// 1024 threads/block; edge-pair vectorized loads (chunk is even).
__global__ __launch_bounds__(1024) void hist_k(const int* ei, unsigned int* gh,
                                               int E, int NB, int chunk,
                                               const int* flags) {
    __shared__ unsigned int lh[1024];
    for (int b = threadIdx.x; b < 1024; b += 1024) lh[b] = 0u;
    __syncthreads();
    int i64f = flags[1];
    int blk = blockIdx.x;
    int s = blk * chunk;
    int t = min(s + chunk, E);
    for (int i = s + threadIdx.x * 2; i < t; i += 2048) {
        if (i + 1 < t) {
            int c0, c1; load_col2(ei, i, E, i64f, c0, c1);
            atomicAdd(&lh[c0 >> BKT_SHIFT], 1u);
            atomicAdd(&lh[c1 >> BKT_SHIFT], 1u);
        } else {
            int c = load_col(ei, i, E, i64f);
            atomicAdd(&lh[c >> BKT_SHIFT], 1u);
        }
    }
    __syncthreads();
    for (int b = threadIdx.x; b < NB; b += 1024)
        gh[(size_t)b * GB + blk] = lh[b];     // bucket-major, block-minor
}

// ---------- scans (for the gh table) ----------
__global__ void scan1_k(const int* counts, int* offsets, int* partials, int n) {
    __shared__ int buf[SCAN_BS];
    int t = threadIdx.x, g = blockIdx.x * SCAN_BS + t;
    int v = (g < n) ? counts[g] : 0;
    buf[t] = v; __syncthreads();
    for (int off = 1; off < SCAN_BS; off <<= 1) {
        int x = (t >= off) ? buf[t - off] : 0;
        __syncthreads();
        buf[t] += x;
        __syncthreads();
    }
    if (g < n) offsets[g] = buf[t] - v;                 // exclusive
    if (t == SCAN_BS - 1) partials[blockIdx.x] = buf[t];
}

__global__ void scan2_k(int* partials, int n) {         // n <= 1024
    __shared__ int buf[SCAN_BS];
    int t = threadIdx.x;
    int v = (t < n) ? partials[t] : 0;
    buf[t] = v; __syncthreads();
    for (int off = 1; off < SCAN_BS; off <<= 1) {
        int x = (t >= off) ? buf[t - off] : 0;
        __syncthreads();
        buf[t] += x;
        __syncthreads();
    }
    if (t < n) partials[t] = buf[t] - v;                // exclusive
}

__global__ void scan3_k(int* offsets, const int* partials, int n) {
    int g = blockIdx.x * SCAN_BS + threadIdx.x;
    if (g < n) offsets[g] += partials[blockIdx.x];
}

// ---------- pass B: scatter edges into bucket-grouped 8B packed records ----
// Record: u64 = w_bits<<32 | row<<7 | (col & 127).  Edge-pair vectorized.
__global__ __launch_bounds__(1024) void scatter_k(const int* ei, const void* w,
                                                  const unsigned int* gh,
                                                  unsigned long long* rc,
                                                  int E, int NB, int chunk,
                                                  const int* flags) {
    __shared__ unsigned int cur[1024];
    int blk = blockIdx.x;
    for (int b = threadIdx.x; b < NB; b += 1024)
        cur[b] = gh[(size_t)b * GB + blk];
    __syncthreads();
    int f32f = flags[0], i64f = flags[1];
    int s = blk * chunk, t = min(s + chunk, E);
    for (int i = s + threadIdx.x * 2; i < t; i += 2048) {
        if (i + 1 < t) {
            int c0, c1, r0, r1; float w0, w1;
            load_col2(ei, i, E, i64f, c0, c1);
            load_row2(ei, i, i64f, r0, r1);
            load_w2(w, i, f32f, w0, w1);
            unsigned int p0 = atomicAdd(&cur[c0 >> BKT_SHIFT], 1u);
            rc[p0] = ((unsigned long long)(unsigned int)__float_as_int(w0) << 32) |
                     (unsigned int)((r0 << 7) | (c0 & (BKT_W - 1)));
            unsigned int p1 = atomicAdd(&cur[c1 >> BKT_SHIFT], 1u);
            rc[p1] = ((unsigned long long)(unsigned int)__float_as_int(w1) << 32) |
                     (unsigned int)((r1 << 7) | (c1 & (BKT_W - 1)));
        } else {
            int c = load_col(ei, i, E, i64f);
            int r = load_row(ei, i, i64f);
            float wf = load_w(w, i, f32f);
            unsigned int pos = atomicAdd(&cur[c >> BKT_SHIFT], 1u);
            rc[pos] = ((unsigned long long)(unsigned int)__float_as_int(wf) << 32) |
                      (unsigned int)((r << 7) | (c & (BKT_W - 1)));
        }
    }
}

// ---------- merged per-bucket finalize: count + local scan + place ----------
__global__ __launch_bounds__(256) void bucket_fin_k(const unsigned long long* rc,
                                                    const unsigned int* gh,
                                                    float* dinv,
                                                    int* offsets, int2* edata,
                                                    int E, int N, int NB) {
    __shared__ unsigned long long pk[BKT_W];
    __shared__ unsigned int sc[BKT_W];
    __shared__ unsigned int cur[BKT_W];
    int b = blockIdx.x;
    for (int i = threadIdx.x; i < BKT_W; i += 256) pk[i] = 0ULL;
    __syncthreads();
    unsigned int s = gh[(size_t)b * GB];
    unsigned int t = (b + 1 < NB) ? gh[(size_t)(b + 1) * GB] : (unsigned int)E;
    // pass 1: per-col packed (count | fixpoint weighted degree)
    for (unsigned int i = s + threadIdx.x; i < t; i += 256) {
        unsigned long long rec = rc[i];
        float wf = __int_as_float((int)(unsigned int)(rec >> 32));
        unsigned int wq = __float2uint_rn(wf * FIXP);
        atomicAdd(&pk[(unsigned int)rec & (BKT_W - 1)],
                  (1ULL << 32) | (unsigned long long)wq);
    }
    __syncthreads();
    unsigned int val = 0;
    if (threadIdx.x < BKT_W) {
        val = (unsigned int)(pk[threadIdx.x] >> 32);
        sc[threadIdx.x] = val;
    }
    __syncthreads();
    for (int off = 1; off < BKT_W; off <<= 1) {
        unsigned int x = (threadIdx.x < BKT_W && threadIdx.x >= (unsigned)off)
                             ? sc[threadIdx.x - off] : 0u;
        __syncthreads();
        if (threadIdx.x < BKT_W) sc[threadIdx.x] += x;
        __syncthreads();
    }
    if (threadIdx.x < BKT_W) {
        int lc = threadIdx.x;
        int v = (b << BKT_SHIFT) + lc;
        unsigned int off0 = s + sc[lc] - val;           // exclusive, bucket-based
        cur[lc] = off0;
        if (v < N) {
            unsigned long long p = pk[lc];
            float deg = 1.0f + (float)(unsigned int)(p & 0xffffffffULL) * (1.0f / FIXP);
            dinv[v] = rsqrtf(deg);                      // deg >= 1 (self loop)
            offsets[v] = (int)off0;
        }
    }
    if (b == NB - 1 && threadIdx.x == 0) offsets[N] = E;
    __syncthreads();
    // pass 2: place (rc segment is L2-resident from pass 1)
    for (unsigned int i = s + threadIdx.x; i < t; i += 256) {
        unsigned long long rec = rc[i];
        unsigned int lo = (unsigned int)rec;
        unsigned int pos = atomicAdd(&cur[lo & (BKT_W - 1)], 1u);
        int2 o; o.x = (int)(lo >> 7); o.y = (int)(unsigned int)(rec >> 32);
        edata[pos] = o;                                 // (row, w_bits)
    }
}

// ---------- both weight transposes in one launch ----------
__global__ void transpose2_k(const void* W1, const void* W2,
                             unsigned short* Wt1, unsigned short* Wt2,
                             const int* flags) {
    int i = blockIdx.x * 256 + threadIdx.x;             // 0..32767
    int which = i >> 14, j = i & 16383;
    const void* W = which ? W2 : W1;
    unsigned short* Wt = which ? Wt2 : Wt1;
    int k = j >> 7, n = j & 127;
    unsigned short v = flags[0] ? f2bf(((const float*)W)[j])
                                : ((const unsigned short*)W)[j];
    Wt[n * 128 + k] = v;
}

// ---------- GEMM: Y[N,128](bf16) = dinv[r] * (X[N,128] @ W[128,128]) ----------
__global__ __launch_bounds__(256) void gemm_k(const void* X,
                                              const unsigned short* Wt,
                                              const float* dinv,
                                              unsigned short* Y, int ntiles,
                                              const int* flags, int xmode) {
    int wave = blockIdx.x * 4 + (threadIdx.x >> 6);
    if (wave >= ntiles) return;
    int lane = threadIdx.x & 63;
    int m = lane & 15, quad = lane >> 4;
    int rowbase = wave * 16;
    int x_f32 = (xmode == 0) ? flags[0] : 0;

    short8 a[4];
    if (x_f32) {
        const float* xf = (const float*)X;
#pragma unroll
        for (int ks = 0; ks < 4; ++ks) {
            const float* p = xf + (size_t)(rowbase + m) * 128 + ks * 32 + quad * 8;
            float4 u0 = *(const float4*)p;
            float4 u1 = *(const float4*)(p + 4);
            short8 t;
            t[0] = (short)f2bf(u0.x); t[1] = (short)f2bf(u0.y);
            t[2] = (short)f2bf(u0.z); t[3] = (short)f2bf(u0.w);
            t[4] = (short)f2bf(u1.x); t[5] = (short)f2bf(u1.y);
            t[6] = (short)f2bf(u1.z); t[7] = (short)f2bf(u1.w);
            a[ks] = t;
        }
    } else {
        const unsigned short* xh = (const unsigned short*)X;
#pragma unroll
        for (int ks = 0; ks < 4; ++ks)
            a[ks] = *(const short8*)(xh + (size_t)(rowbase + m) * 128 + ks * 32 + quad * 8);
    }

    float dvr[4];
#pragma unroll
    for (int i = 0; i < 4; ++i) dvr[i] = dinv[rowbase + quad * 4 + i];

#pragma unroll
    for (int ct = 0; ct < 8; ++ct) {
        f32x4 acc = {0.f, 0.f, 0.f, 0.f};
#pragma unroll
        for (int ks = 0; ks < 4; ++ks) {
            short8 b = *(const short8*)(Wt + (size_t)(ct * 16 + m) * 128 + ks * 32 + quad * 8);
            acc = __builtin_amdgcn_mfma_f32_16x16x32_bf16(a[ks], b, acc, 0, 0, 0);
        }
#pragma unroll
        for (int i = 0; i < 4; ++i) {
            size_t r = rowbase + quad * 4 + i;
            size_t c = ct * 16 + m;
            Y[r * 128 + c] = f2bf(acc[i] * dvr[i]);
        }
    }
}

// ---------- aggregation: out[v] = act(b + dinv[v]*(sum_e w_e*hs[row_e] + hs[v]))
// hs already carries dinv[row]; self-loop term is exactly hs[v].
// One wave per node — R3/R7 form, measured at the 4 TB/s L2-miss-path ceiling.
__global__ __launch_bounds__(64) void agg_k(const unsigned int* h2,
                                            const int2* edata,
                                            const int* offsets,
                                            const float* dinv,
                                            const void* bias,
                                            void* out,
                                            int relu, int out_bf16,
                                            const int* flags) {
    int v = blockIdx.x;
    int lane = threadIdx.x;
    int2 se = *(const int2*)(offsets + v);
    int start = se.x, end = se.y;
    float a0 = 0.f, a1 = 0.f;

    int e = start;
    for (; e + 4 <= end; e += 4) {
        int2 d0 = edata[e], d1 = edata[e + 1], d2 = edata[e + 2], d3 = edata[e + 3];
        unsigned int u0 = h2[(size_t)d0.x * 64 + lane];
        unsigned int u1 = h2[(size_t)d1.x * 64 + lane];
        unsigned int u2 = h2[(size_t)d2.x * 64 + lane];
        unsigned int u3 = h2[(size_t)d3.x * 64 + lane];
        float c0 = __int_as_float(d0.y), c1 = __int_as_float(d1.y);
        float c2 = __int_as_float(d2.y), c3 = __int_as_float(d3.y);
        float l, h;
        bfx2(u0, l, h); a0 = fmaf(c0, l, a0); a1 = fmaf(c0, h, a1);
        bfx2(u1, l, h); a0 = fmaf(c1, l, a0); a1 = fmaf(c1, h, a1);
        bfx2(u2, l, h); a0 = fmaf(c2, l, a0); a1 = fmaf(c2, h, a1);
        bfx2(u3, l, h); a0 = fmaf(c3, l, a0); a1 = fmaf(c3, h, a1);
    }
    for (; e < end; ++e) {
        int2 d = edata[e];
        float l, h; bfx2(h2[(size_t)d.x * 64 + lane], l, h);
        float c = __int_as_float(d.y);
        a0 = fmaf(c, l, a0); a1 = fmaf(c, h, a1);
    }

    {   // self loop: hs[v] = dinv[v]*h[v], coefficient 1
        float l, h; bfx2(h2[(size_t)v * 64 + lane], l, h);
        a0 += l; a1 += h;
    }
    float dv = dinv[v];
    a0 *= dv; a1 *= dv;
    if (flags[0]) {
        const float* bf = (const float*)bias;
        a0 += bf[2 * lane]; a1 += bf[2 * lane + 1];
    } else {
        float l, h; bfx2(((const unsigned int*)bias)[lane], l, h);
        a0 += l; a1 += h;
    }
    if (relu) { a0 = fmaxf(a0, 0.f); a1 = fmaxf(a1, 0.f); }
    if (out_bf16) {
        ((unsigned int*)out)[(size_t)v * 64 + lane] =
            (unsigned int)f2bf(a0) | ((unsigned int)f2bf(a1) << 16);
    } else {
        float2 r; r.x = a0; r.y = a1;
        ((float2*)out)[(size_t)v * 64 + lane] = r;
    }
}

// ---------- launch ----------
extern "C" void kernel_launch(void* const* d_in, const int* in_sizes, int n_in,
                              void* d_out, int out_size, void* d_ws, size_t ws_size,
                              hipStream_t stream) {
    const void* x  = d_in[0];                 // fp32 (detected) [N,128]
    const int*  ei = (const int*)d_in[1];     // int64/int32 (detected) [2,E]
    const void* ew = d_in[2];                 // fp32 [E]
    const void* W1 = d_in[3];
    const void* b1 = d_in[4];
    const void* W2 = d_in[5];
    const void* b2 = d_in[6];

    const int N = in_sizes[0] / 128;     // 100000
    const int E = in_sizes[2];           // 3200000

    const int NB = (N + BKT_W - 1) >> BKT_SHIFT;   // 782 buckets
    if (NB > 1024) return;                         // design limit N <= 131072 (row fits 17 bits)
    const int M = NB * GB;                         // gh table entries (200192)
    const int chunk = (((E + GB - 1) / GB) + 1) & ~1;   // even, for pair loads

    auto align = [](size_t v) { return (v + 255) & ~(size_t)255; };
    // rc (8B packed records) aliases h/a1: records dead before gemm writes h.
    size_t rc_bytes = align((size_t)E * 8);
    size_t ha_bytes = 2 * align((size_t)N * 128 * 2);
    size_t regionX  = rc_bytes > ha_bytes ? rc_bytes : ha_bytes;
    size_t need = align((size_t)E * 8)            // edata
                + regionX                         // rc | h,a1
                + align((size_t)M * 4)            // gh
                + align((size_t)(N + 1) * 4)      // offsets (N+1)
                + align((size_t)N * 4)            // dinv
                + align(SCAN_BS * 4) + align(256) // partials, flags
                + align(128 * 128 * 2) * 2;       // Wt1, Wt2
    if (ws_size < need) return;  // diagnostic: zeros -> absmax 0.3613

    char* p = (char*)d_ws;
    int2*  edata = (int2*)p;                     p += align((size_t)E * 8);
    char*  rx = p;                               p += regionX;
    unsigned long long* rc = (unsigned long long*)rx;
    unsigned short* h  = (unsigned short*)rx;
    unsigned short* a1 = (unsigned short*)(rx + align((size_t)N * 128 * 2));
    unsigned int* gh = (unsigned int*)p;         p += align((size_t)M * 4);
    int*   offsets  = (int*)p;                   p += align((size_t)(N + 1) * 4);
    float* dinv     = (float*)p;                 p += align((size_t)N * 4);
    int*   partials = (int*)p;                   p += align(SCAN_BS * 4);
    int*   flags    = (int*)p;                   p += align(256);
    unsigned short* Wt1 = (unsigned short*)p;    p += align(128 * 128 * 2);
    unsigned short* Wt2 = (unsigned short*)p;    p += align(128 * 128 * 2);

    const int nsbM = (M + SCAN_BS - 1) / SCAN_BS;    // 196

    detect_k<<<1, 256, 0, stream>>>((const unsigned int*)x, (const unsigned int*)ei, flags);

    // ---- bucket sort (no global atomics anywhere) ----
    hist_k<<<GB, 1024, 0, stream>>>(ei, gh, E, NB, chunk, flags);
    scan1_k<<<nsbM, SCAN_BS, 0, stream>>>((const int*)gh, (int*)gh, partials, M);
    scan2_k<<<1, SCAN_BS, 0, stream>>>(partials, nsbM);
    scan3_k<<<nsbM, SCAN_BS, 0, stream>>>((int*)gh, partials, M);
    scatter_k<<<GB, 1024, 0, stream>>>(ei, ew, gh, rc, E, NB, chunk, flags);
    bucket_fin_k<<<NB, 256, 0, stream>>>(rc, gh, dinv, offsets, edata, E, N, NB);

    transpose2_k<<<128, 256, 0, stream>>>(W1, W2, Wt1, Wt2, flags);

    const int ntiles = N / 16;                       // 6250
    const int gGemm = (ntiles + 3) / 4;

    // layer 1: hs = dinv*(x@W1) ; a1 = relu(agg(hs) + b1)
    gemm_k<<<gGemm, 256, 0, stream>>>(x, Wt1, dinv, h, ntiles, flags, /*xmode=*/0);
    agg_k<<<N, 64, 0, stream>>>((const unsigned int*)h, edata, offsets, dinv,
                                b1, a1, /*relu=*/1, /*out_bf16=*/1, flags);

    // layer 2: hs = dinv*(a1@W2) ; out = agg(hs) + b2  (fp32 out)
    gemm_k<<<gGemm, 256, 0, stream>>>(a1, Wt2, dinv, h, ntiles, flags, /*xmode=*/1);
    agg_k<<<N, 64, 0, stream>>>((const unsigned int*)h, edata, offsets, dinv,
                                b2, d_out, /*relu=*/0, /*out_bf16=*/0, flags);
}